// Round 1
// baseline (232.025 us; speedup 1.0000x reference)
//
#include <hip/hip_runtime.h>
#include <hip/hip_bf16.h>

#define HEADS 4
#define HEAD_DIM 32
#define SLAB 128   // per-dst col slab capacity (deg ~ Poisson(16); max seen ~45)

typedef __bf16 bf16x8 __attribute__((ext_vector_type(8)));
typedef float  f32x4  __attribute__((ext_vector_type(4)));
typedef _Float16 h2   __attribute__((ext_vector_type(2)));

// float -> bf16 (RNE)
__device__ __forceinline__ unsigned short f2bf(float f) {
    unsigned u = __float_as_uint(f);
    u += 0x7fffu + ((u >> 16) & 1u);
    return (unsigned short)(u >> 16);
}
__device__ __forceinline__ unsigned pack2bf(float a, float b) {
    return (unsigned)f2bf(a) | ((unsigned)f2bf(b) << 16);
}
__device__ __forceinline__ unsigned short f2h(float f) {
    _Float16 h = (_Float16)f;
    return *(unsigned short*)&h;
}

// ---------------------------------------------------------------------------
// fillw: blocks 0..31 -> conv_w (4 matrices x 2048 threads, kg 0..15);
//        blocks >=32  -> bucket CSR fill: pos = atomicAdd(cnt[dst]),
//                        col[dst*SLAB+pos] = src  (no scan, no rowptr).
// Wsw[m][kg*1024 + n*8 + j] = W[(kg*8+j)*128 + n]
// ---------------------------------------------------------------------------
__global__ __launch_bounds__(256) void fillw_kernel(
    const float* __restrict__ W0, const float* __restrict__ W1,
    const float* __restrict__ W2, const float* __restrict__ W3,
    unsigned short* __restrict__ Wsw,
    const int* __restrict__ edge, int E,
    int* __restrict__ cnt, int* __restrict__ col)
{
    if (blockIdx.x < 32) {
        const float* Wm[4] = { W0, W1, W2, W3 };
        int mi = blockIdx.x >> 3;                        // 0..3
        const float* __restrict__ W = Wm[mi];
        unsigned short* __restrict__ o = Wsw + (size_t)mi * 16384;
        int t = (blockIdx.x & 7) * 256 + threadIdx.x;    // 0..2047
        int kg = t >> 7;                                 // 0..15
        int n  = t & 127;                                // 0..127
        ushort4 p0, p1;
        p0.x = f2bf(W[(kg * 8 + 0) * 128 + n]);
        p0.y = f2bf(W[(kg * 8 + 1) * 128 + n]);
        p0.z = f2bf(W[(kg * 8 + 2) * 128 + n]);
        p0.w = f2bf(W[(kg * 8 + 3) * 128 + n]);
        p1.x = f2bf(W[(kg * 8 + 4) * 128 + n]);
        p1.y = f2bf(W[(kg * 8 + 5) * 128 + n]);
        p1.z = f2bf(W[(kg * 8 + 6) * 128 + n]);
        p1.w = f2bf(W[(kg * 8 + 7) * 128 + n]);
        *(ushort4*)(o + kg * 1024 + n * 8)     = p0;
        *(ushort4*)(o + kg * 1024 + n * 8 + 4) = p1;
    } else {
        int e = (blockIdx.x - 32) * 256 + threadIdx.x;
        if (e < E) {
            int dst = edge[E + e];
            int src = edge[e];
            int pos = atomicAdd(&cnt[dst], 1);
            if (pos < SLAB)
                col[(size_t)dst * SLAB + pos] = src;
        }
    }
}

// ---------------------------------------------------------------------------
// MFMA 64x128x128 tile: 256 thr / 4 waves, wave tile 32x64.
// As: LDS, 64 rows x stride 136 bf16.
// B:  read DIRECTLY from global swizzled layout (L2-resident, 32KB/matrix):
//     Bsw[kg*1024 + n*8 + j];  fragment = Bsw + (kk*4+quad)*1024 + n*8.
// ---------------------------------------------------------------------------
__device__ __forceinline__ void mfma_compute64g(
    const unsigned short* As, const unsigned short* __restrict__ Bsw,
    f32x4 (&acc)[2][4], int mb, int nb, int quad, int l16)
{
    #pragma unroll
    for (int a = 0; a < 2; a++)
        #pragma unroll
        for (int b = 0; b < 4; b++)
            #pragma unroll
            for (int e = 0; e < 4; e++) acc[a][b][e] = 0.f;

    #pragma unroll
    for (int kk = 0; kk < 4; kk++) {
        bf16x8 af[2], bf[4];
        #pragma unroll
        for (int mt = 0; mt < 2; mt++)
            af[mt] = *(const bf16x8*)(As + (mb + mt * 16 + l16) * 136
                                         + kk * 32 + quad * 8);
        #pragma unroll
        for (int nt = 0; nt < 4; nt++)
            bf[nt] = *(const bf16x8*)(Bsw + (kk * 4 + quad) * 1024
                                          + (nb + nt * 16 + l16) * 8);
        #pragma unroll
        for (int mt = 0; mt < 2; mt++)
            #pragma unroll
            for (int nt = 0; nt < 4; nt++)
                acc[mt][nt] = __builtin_amdgcn_mfma_f32_16x16x32_bf16(
                    af[mt], bf[nt], acc[mt][nt], 0, 0, 0);
    }
}

// ---------------------------------------------------------------------------
// qkv: 64-row tile, x staged ONCE (fp32 -> bf16 at LDS write), 3 modes
// back-to-back with NO inter-mode barriers (B direct from global).
// ALL outputs f16 now (q,k for fdot2; v for v_fma_mix in attn).
// ---------------------------------------------------------------------------
__global__ __launch_bounds__(256) void qkv_kernel(
    const float* __restrict__ x, const unsigned short* __restrict__ Wsw,
    unsigned short* __restrict__ qh, unsigned short* __restrict__ kh,
    unsigned short* __restrict__ vh, int M)
{
    __shared__ __align__(16) unsigned short As[64 * 136];
    const int r0 = blockIdx.x * 64;
    const int t  = threadIdx.x;

    #pragma unroll
    for (int it = 0; it < 4; it++) {
        int c   = t + it * 256;          // 0..1023
        int row = c >> 4, kp = c & 15;   // 8 bf16 elems per thread
        float4 a = make_float4(0.f, 0.f, 0.f, 0.f);
        float4 b = make_float4(0.f, 0.f, 0.f, 0.f);
        if (r0 + row < M) {
            a = *(const float4*)(x + (size_t)(r0 + row) * 128 + kp * 8);
            b = *(const float4*)(x + (size_t)(r0 + row) * 128 + kp * 8 + 4);
        }
        uint4 pk;
        pk.x = pack2bf(a.x, a.y);
        pk.y = pack2bf(a.z, a.w);
        pk.z = pack2bf(b.x, b.y);
        pk.w = pack2bf(b.z, b.w);
        *(uint4*)(As + row * 136 + kp * 8) = pk;
    }
    __syncthreads();

    const int wave = t >> 6, L = t & 63;
    const int quad = L >> 4, l16 = L & 15;
    const int mb = (wave >> 1) * 32;
    const int nb = (wave & 1) * 64;

    #pragma unroll
    for (int mode = 0; mode < 3; mode++) {
        f32x4 acc[2][4];
        mfma_compute64g(As, Wsw + (size_t)mode * 16384, acc, mb, nb, quad, l16);

        unsigned short* ob = (mode == 0) ? qh : (mode == 1) ? kh : vh;
        #pragma unroll
        for (int mt = 0; mt < 2; mt++) {
            #pragma unroll
            for (int nt = 0; nt < 4; nt++) {
                int colj = nb + nt * 16 + l16;
                #pragma unroll
                for (int r = 0; r < 4; r++) {
                    int row = r0 + mb + mt * 16 + quad * 4 + r;
                    if (row < M)
                        ob[(size_t)row * 128 + colj] = f2h(acc[mt][nt][r]);
                }
            }
        }
    }
}

// out: relu(aggh @ Wout + bout) + x   (64-row tile, B direct from global)
__global__ __launch_bounds__(256) void out_mfma_kernel(
    const unsigned short* __restrict__ aggh, const unsigned short* __restrict__ Wsw,
    const float* __restrict__ bout, const float* __restrict__ x,
    float* __restrict__ out, int M)
{
    __shared__ __align__(16) unsigned short As[64 * 136];
    const int r0 = blockIdx.x * 64;
    const int t  = threadIdx.x;

    #pragma unroll
    for (int it = 0; it < 4; it++) {
        int c   = t + it * 256;
        int row = c >> 4, kp = c & 15;
        uint4 val = make_uint4(0, 0, 0, 0);
        if (r0 + row < M)
            val = *(const uint4*)(aggh + (size_t)(r0 + row) * 128 + kp * 8);
        *(uint4*)(As + row * 136 + kp * 8) = val;
    }
    __syncthreads();

    const int wave = t >> 6, L = t & 63;
    const int quad = L >> 4, l16 = L & 15;
    const int mb = (wave >> 1) * 32;
    const int nb = (wave & 1) * 64;

    f32x4 acc[2][4];
    mfma_compute64g(As, Wsw, acc, mb, nb, quad, l16);

    #pragma unroll
    for (int mt = 0; mt < 2; mt++) {
        #pragma unroll
        for (int nt = 0; nt < 4; nt++) {
            int colj = nb + nt * 16 + l16;
            float b = bout[colj];
            #pragma unroll
            for (int r = 0; r < 4; r++) {
                int row = r0 + mb + mt * 16 + quad * 4 + r;
                if (row < M) {
                    float val = fmaxf(acc[mt][nt][r] + b, 0.f)
                              + x[(size_t)row * 128 + colj];
                    out[(size_t)row * 128 + colj] = val;
                }
            }
        }
    }
}

// ---------------------------------------------------------------------------
// attn v2: single-pass online-softmax, 4 dst per block, one wave each.
// - no LDS at all (kbuf staging removed: k loaded per-lane direct; ev/src
//   broadcast via shfl)
// - cnt/col/q loads issued in parallel (col read unconditionally, clamped
//   after arrival -> one fewer serial global round-trip)
// - score role: lane = eo*4+h (edge-in-chunk, head); 16 fdot2, 4 split chains
// - v role: half = lane>>5 (edge parity), li = lane&31 -> cols 4li..4li+3;
//   2 edges per coalesced uint2 load instruction; v is f16 -> fma_mix
// ---------------------------------------------------------------------------
__global__ __launch_bounds__(256, 8) void attn_kernel(
    const unsigned short* __restrict__ qhB, const unsigned short* __restrict__ kh,
    const unsigned short* __restrict__ vh,
    const int* __restrict__ cnt, const int* __restrict__ col,
    unsigned short* __restrict__ aggh, int N)
{
    const int wv   = threadIdx.x >> 6;
    const int lane = threadIdx.x & 63;
    const int dst  = blockIdx.x * 4 + wv;
    if (dst >= N) return;

    const size_t orow = (size_t)dst * 128;
    const size_t slab = (size_t)dst * SLAB;

    const int h    = lane & 3;           // score role: head
    const int eo   = lane >> 2;          // score role: edge in chunk
    const int half = lane >> 5;          // v role: edge parity
    const int li   = lane & 31;          // v role: col group (4 cols)
    const int hvv  = li >> 3;            // v role: head of my cols

    // --- independent loads, all issued before any dependent use ---
    const int degr = cnt[dst];
    const int colv = col[slab + lane];   // unconditional; clamped below
    uint4 qreg[4];
    {
        const uint4* qp = (const uint4*)(qhB + orow + h * HEAD_DIM);
        qreg[0] = qp[0]; qreg[1] = qp[1]; qreg[2] = qp[2]; qreg[3] = qp[3];
    }
    const h2* qv = (const h2*)qreg;      // 16 h2 entries

    const int deg = min(degr, SLAB);
    if (deg == 0) {
        *(unsigned*)(aggh + orow + 2 * lane) = 0u;
        return;
    }
    const int srcA = (lane < deg) ? colv : 0;
    int srcB = 0;
    if (64 + lane < deg) srcB = col[slab + 64 + lane];

    float m_p  = -1e30f;                 // running per-head max (score role)
    float dsum = 0.f;                    // running denom (v role, head hvv)
    float a0 = 0.f, a1 = 0.f, a2 = 0.f, a3 = 0.f;

    const int nchunk = (deg + 15) >> 4;
    for (int c = 0; c < nchunk; ++c) {
        const int nle  = min(16, deg - c * 16);
        const int csrc = (c < 4) ? srcA : srcB;
        const int lsel = (c & 3) * 16;

        // ---- scores: direct per-lane k head-slice load, 16 fdot2 ----
        const int sr = __shfl(csrc, lsel + eo);
        uint4 kreg[4];
        {
            const uint4* kp = (const uint4*)(kh + (size_t)sr * 128 + h * HEAD_DIM);
            kreg[0] = kp[0]; kreg[1] = kp[1]; kreg[2] = kp[2]; kreg[3] = kp[3];
        }
        const h2* kv = (const h2*)kreg;
        float s0 = 0.f, s1 = 0.f, s2 = 0.f, s3 = 0.f;
        #pragma unroll
        for (int j = 0; j < 4; ++j) {
#if __has_builtin(__builtin_amdgcn_fdot2)
            s0 = __builtin_amdgcn_fdot2(qv[j],      kv[j],      s0, false);
            s1 = __builtin_amdgcn_fdot2(qv[4 + j],  kv[4 + j],  s1, false);
            s2 = __builtin_amdgcn_fdot2(qv[8 + j],  kv[8 + j],  s2, false);
            s3 = __builtin_amdgcn_fdot2(qv[12 + j], kv[12 + j], s3, false);
#else
            h2 w0 = qv[j] * kv[j],         w1 = qv[4 + j] * kv[4 + j];
            h2 w2 = qv[8 + j] * kv[8 + j], w3 = qv[12 + j] * kv[12 + j];
            s0 += (float)w0[0] + (float)w0[1];
            s1 += (float)w1[0] + (float)w1[1];
            s2 += (float)w2[0] + (float)w2[1];
            s3 += (float)w3[0] + (float)w3[1];
#endif
        }
        float s = (s0 + s1) + (s2 + s3);
        s = (eo < nle) ? s : -1e30f;

        // chunk per-head max across the 16 edge lanes of this head
        float cm = s;
        #pragma unroll
        for (int off = 4; off < 64; off <<= 1)
            cm = fmaxf(cm, __shfl_xor(cm, off));

        const float mp_new   = fmaxf(m_p, cm);
        const float scale_p  = __expf(m_p - mp_new);   // 0 on first chunk
        const float ev = (eo < nle) ? __expf(s - mp_new) : 0.f;
        m_p = mp_new;

        // chunk per-head denom
        float cs = ev;
        #pragma unroll
        for (int off = 4; off < 64; off <<= 1)
            cs += __shfl_xor(cs, off);

        // rescale running state into v role (head hvv)
        const float scale = __shfl(scale_p, hvv);
        const float cs_v  = __shfl(cs, hvv);
        dsum = dsum * scale + cs_v;
        a0 *= scale; a1 *= scale; a2 *= scale; a3 *= scale;

        // ---- v accumulate: 2 edges per instruction, f16 fma_mix ----
        const int nj = (nle + 1) >> 1;
        for (int jj = 0; jj < nj; ++jj) {
            const int   j  = 2 * jj + half;            // 0..15 (may be == nle-pad, w=0)
            const int   sj = __shfl(csrc, lsel + j);
            const float w  = __shfl(ev, j * 4 + hvv);
            const uint2 uv = *(const uint2*)(vh + (size_t)sj * 128 + 4 * li);
            const h2 va = __builtin_bit_cast(h2, uv.x);
            const h2 vb = __builtin_bit_cast(h2, uv.y);
            a0 = fmaf(w, (float)va[0], a0);
            a1 = fmaf(w, (float)va[1], a1);
            a2 = fmaf(w, (float)vb[0], a2);
            a3 = fmaf(w, (float)vb[1], a3);
        }
    }

    // merge edge-parity halves (lanes l and l+32 hold same cols)
    a0 += __shfl_xor(a0, 32);
    a1 += __shfl_xor(a1, 32);
    a2 += __shfl_xor(a2, 32);
    a3 += __shfl_xor(a3, 32);

    const float inv = __builtin_amdgcn_rcpf(dsum);
    a0 *= inv; a1 *= inv; a2 *= inv; a3 *= inv;

    // redistribute 4-cols/lane -> 2-cols/lane, pack bf16, coalesced store
    const int sl = lane >> 1;
    const float b0 = __shfl(a0, sl);
    const float b1 = __shfl(a1, sl);
    const float b2 = __shfl(a2, sl);
    const float b3 = __shfl(a3, sl);
    const float o0 = (lane & 1) ? b2 : b0;
    const float o1 = (lane & 1) ? b3 : b1;
    *(unsigned*)(aggh + orow + 2 * lane) = pack2bf(o0, o1);
}

// ---------------------------------------------------------------------------
extern "C" void kernel_launch(void* const* d_in, const int* in_sizes, int n_in,
                              void* d_out, int out_size, void* d_ws, size_t ws_size,
                              hipStream_t stream)
{
    const float* x    = (const float*)d_in[0];
    const int*   edge = (const int*)d_in[1];   // [2, E]
    const float* Wt   = (const float*)d_in[2];
    const float* Ws   = (const float*)d_in[3];
    const float* Wc   = (const float*)d_in[4];
    const float* Wout = (const float*)d_in[5];
    const float* bout = (const float*)d_in[6];
    float* out = (float*)d_out;

    const int N = in_sizes[0] / 128;
    const int E = in_sizes[1] / 2;

    // workspace: ushort regions (16B aligned), then ints
    unsigned short* qh   = (unsigned short*)d_ws;
    unsigned short* kh   = qh   + (size_t)N * 128;
    unsigned short* vh   = kh   + (size_t)N * 128;
    unsigned short* aggh = vh   + (size_t)N * 128;
    unsigned short* Wsw  = aggh + (size_t)N * 128;   // 4 * 16384
    int* cnt  = (int*)(Wsw + 4 * 16384);
    int* colb = cnt + ((N + 3) & ~3);

    hipMemsetAsync(cnt, 0, (size_t)N * sizeof(int), stream);

    const int gE   = (E + 255) / 256;
    const int gM64 = (N + 63) / 64;

    fillw_kernel<<<32 + gE, 256, 0, stream>>>(Wt, Ws, Wc, Wout, Wsw,
                                              edge, E, cnt, colb);
    qkv_kernel<<<gM64, 256, 0, stream>>>(x, Wsw, qh, kh, vh, N);
    attn_kernel<<<(N + 3) / 4, 256, 0, stream>>>(qh, kh, vh, cnt, colb, aggh, N);
    out_mfma_kernel<<<gM64, 256, 0, stream>>>(aggh, Wsw + 3 * 16384, bout, x, out, N);
}